// Round 1
// baseline (3076.942 us; speedup 1.0000x reference)
//
#include <hip/hip_runtime.h>

#define N_NODES 50000
#define N_EDGES 800000
#define DIM 64
#define N_GRAPH 512
#define N_CLASS 10

// ---------------- degree ----------------
__global__ void deg_kernel(const int* __restrict__ dst_sc,
                           const int* __restrict__ dst_fc,
                           float* __restrict__ deg_sc,
                           float* __restrict__ deg_fc) {
    int i = blockIdx.x * blockDim.x + threadIdx.x;
    if (i < N_EDGES) {
        atomicAdd(&deg_sc[dst_sc[i]], 1.0f);
        atomicAdd(&deg_fc[dst_fc[i]], 1.0f);
    }
}

__global__ void inv_kernel(float* __restrict__ deg_sc, float* __restrict__ deg_fc) {
    int i = blockIdx.x * blockDim.x + threadIdx.x;
    if (i < N_NODES) {
        deg_sc[i] = 1.0f / fmaxf(deg_sc[i], 1.0f);
        deg_fc[i] = 1.0f / fmaxf(deg_fc[i], 1.0f);
    }
}

// ---------------- scatter-add aggregation ----------------
// one edge handled by 16 threads, each doing a float4 chunk of the 64-dim row
__global__ void scatter_kernel(const int* __restrict__ src,
                               const int* __restrict__ dst,
                               const float* __restrict__ x,
                               float* __restrict__ agg) {
    int tid = blockIdx.x * blockDim.x + threadIdx.x;
    int e = tid >> 4;
    int c = (tid & 15) << 2;
    if (e < N_EDGES) {
        int s = src[e];
        int d = dst[e];
        const float4 v = *(const float4*)(x + (size_t)s * DIM + c);
        float* o = agg + (size_t)d * DIM + c;
        atomicAdd(o + 0, v.x);
        atomicAdd(o + 1, v.y);
        atomicAdd(o + 2, v.z);
        atomicAdd(o + 3, v.w);
    }
}

// ---------------- (agg * inv) @ W + b, relu ----------------
// block = 256 threads = 4 nodes x 64 output features; W staged in LDS
__global__ void linear_relu_kernel(const float* __restrict__ agg,
                                   const float* __restrict__ inv,
                                   const float* __restrict__ W,
                                   const float* __restrict__ b,
                                   float* __restrict__ out) {
    __shared__ float Ws[DIM * DIM];
    int t = threadIdx.x;
    for (int k = t; k < DIM * DIM; k += 256) Ws[k] = W[k];
    __syncthreads();
    int n = blockIdx.x * 4 + (t >> 6);
    int j = t & 63;
    if (n < N_NODES) {
        const float* a = agg + (size_t)n * DIM;
        float sum = 0.0f;
#pragma unroll
        for (int d = 0; d < DIM; ++d) sum += a[d] * Ws[d * DIM + j];
        sum = sum * inv[n] + b[j];
        out[(size_t)n * DIM + j] = fmaxf(sum, 0.0f);
    }
}

// ---------------- projection + graph scatter ----------------
// thread handles (node, class); c in [0,16), classes 10..15 idle
__global__ void proj_kernel(const float* __restrict__ x0,
                            const float* __restrict__ x1,
                            const float* __restrict__ Wout,
                            const int* __restrict__ batch,
                            float* __restrict__ gsum,
                            float* __restrict__ gcnt) {
    __shared__ float Ws[DIM * N_CLASS];
    int t = threadIdx.x;
    for (int k = t; k < DIM * N_CLASS; k += 256) Ws[k] = Wout[k];
    __syncthreads();
    int tid = blockIdx.x * blockDim.x + t;
    int n = tid >> 4;
    int c = tid & 15;
    if (n < N_NODES && c < N_CLASS) {
        const float* a = x0 + (size_t)n * DIM;
        const float* bx = x1 + (size_t)n * DIM;
        float sum = 0.0f;
#pragma unroll
        for (int d = 0; d < DIM; ++d) sum += (a[d] + bx[d]) * Ws[d * N_CLASS + c];
        int g = batch[n];
        atomicAdd(&gsum[g * N_CLASS + c], sum * 0.5f);
        if (c == 0) atomicAdd(&gcnt[g], 1.0f);
    }
}

__global__ void finalize_kernel(float* __restrict__ out,
                                const float* __restrict__ gcnt,
                                const float* __restrict__ bout) {
    int i = blockIdx.x * blockDim.x + threadIdx.x;
    if (i < N_GRAPH * N_CLASS) {
        float c = gcnt[i / N_CLASS];
        out[i] = (c > 0.0f) ? (out[i] / c + bout[i % N_CLASS]) : 0.0f;
    }
}

extern "C" void kernel_launch(void* const* d_in, const int* in_sizes, int n_in,
                              void* d_out, int out_size, void* d_ws, size_t ws_size,
                              hipStream_t stream) {
    const float* x    = (const float*)d_in[0];
    const float* W0   = (const float*)d_in[1];
    const float* b0   = (const float*)d_in[2];
    const float* W1   = (const float*)d_in[3];
    const float* b1   = (const float*)d_in[4];
    const float* Wout = (const float*)d_in[5];
    const float* bout = (const float*)d_in[6];
    const int* ei_sc  = (const int*)d_in[7];
    const int* ei_fc  = (const int*)d_in[8];
    const int* batch  = (const int*)d_in[9];

    const int* src_sc = ei_sc;
    const int* dst_sc = ei_sc + N_EDGES;
    const int* src_fc = ei_fc;
    const int* dst_fc = ei_fc + N_EDGES;

    // workspace layout (floats)
    float* ws = (float*)d_ws;
    float* bufA   = ws;                          // N*DIM  (aggregation target)
    float* bufB   = bufA + (size_t)N_NODES * DIM; // N*DIM  (branch sc hidden/out)
    float* bufC   = bufB + (size_t)N_NODES * DIM; // N*DIM  (branch fc hidden/out)
    float* inv_sc = bufC + (size_t)N_NODES * DIM; // N
    float* inv_fc = inv_sc + N_NODES;             // N
    float* gcnt   = inv_fc + N_NODES;             // G
    // total ~38.8 MB

    float* gout = (float*)d_out;

    const int BLK = 256;
    dim3 blk(BLK);
    int grid_E   = (N_EDGES + BLK - 1) / BLK;          // per-edge
    int grid_E16 = (N_EDGES * 16 + BLK - 1) / BLK;     // 16 threads/edge
    int grid_N   = (N_NODES + BLK - 1) / BLK;
    int grid_N4  = (N_NODES + 3) / 4;                  // linear_relu: 4 nodes/block
    int grid_N16 = (N_NODES * 16 + BLK - 1) / BLK;     // proj
    size_t aggBytes = (size_t)N_NODES * DIM * sizeof(float);

    // zero deg buffers + gcnt (contiguous region) and output
    hipMemsetAsync(inv_sc, 0, (2 * (size_t)N_NODES + N_GRAPH) * sizeof(float), stream);
    hipMemsetAsync(d_out, 0, (size_t)N_GRAPH * N_CLASS * sizeof(float), stream);

    deg_kernel<<<grid_E, blk, 0, stream>>>(dst_sc, dst_fc, inv_sc, inv_fc);
    inv_kernel<<<grid_N, blk, 0, stream>>>(inv_sc, inv_fc);

    // ---- branch sc, layer 0 ----
    hipMemsetAsync(bufA, 0, aggBytes, stream);
    scatter_kernel<<<grid_E16, blk, 0, stream>>>(src_sc, dst_sc, x, bufA);
    linear_relu_kernel<<<grid_N4, blk, 0, stream>>>(bufA, inv_sc, W0, b0, bufB);
    // ---- branch sc, layer 1 ----
    hipMemsetAsync(bufA, 0, aggBytes, stream);
    scatter_kernel<<<grid_E16, blk, 0, stream>>>(src_sc, dst_sc, bufB, bufA);
    linear_relu_kernel<<<grid_N4, blk, 0, stream>>>(bufA, inv_sc, W0 + DIM * DIM, b0 + DIM, bufB);

    // ---- branch fc, layer 0 ----
    hipMemsetAsync(bufA, 0, aggBytes, stream);
    scatter_kernel<<<grid_E16, blk, 0, stream>>>(src_fc, dst_fc, x, bufA);
    linear_relu_kernel<<<grid_N4, blk, 0, stream>>>(bufA, inv_fc, W1, b1, bufC);
    // ---- branch fc, layer 1 ----
    hipMemsetAsync(bufA, 0, aggBytes, stream);
    scatter_kernel<<<grid_E16, blk, 0, stream>>>(src_fc, dst_fc, bufC, bufA);
    linear_relu_kernel<<<grid_N4, blk, 0, stream>>>(bufA, inv_fc, W1 + DIM * DIM, b1 + DIM, bufC);

    // ---- projection + graph reduce ----
    proj_kernel<<<grid_N16, blk, 0, stream>>>(bufB, bufC, Wout, batch, gout, gcnt);
    finalize_kernel<<<(N_GRAPH * N_CLASS + BLK - 1) / BLK, blk, 0, stream>>>(gout, gcnt, bout);
}

// Round 2
// 750.237 us; speedup vs baseline: 4.1013x; 4.1013x over previous
//
#include <hip/hip_runtime.h>

#define N_NODES 50000
#define N_EDGES 800000
#define DIM 64
#define N_GRAPH 512
#define N_CLASS 10
#define SCAN_T 1024

// ---------------- integer degree (both branches) ----------------
__global__ void deg_kernel(const int* __restrict__ dst_sc,
                           const int* __restrict__ dst_fc,
                           int* __restrict__ deg_sc,
                           int* __restrict__ deg_fc) {
    int i = blockIdx.x * blockDim.x + threadIdx.x;
    if (i < N_EDGES) {
        atomicAdd(&deg_sc[dst_sc[i]], 1);
        atomicAdd(&deg_fc[dst_fc[i]], 1);
    }
}

// ---------------- exclusive scan (single block) + inv_deg ----------------
__global__ void scan_kernel(const int* __restrict__ deg,
                            int* __restrict__ row,
                            float* __restrict__ inv) {
    __shared__ int sums[SCAN_T];
    const int chunk = (N_NODES + SCAN_T - 1) / SCAN_T;  // 49
    int t = threadIdx.x;
    int lo = t * chunk;
    int hi = min(lo + chunk, N_NODES);
    int s = 0;
    for (int i = lo; i < hi; ++i) s += deg[i];
    sums[t] = s;
    __syncthreads();
    // Hillis-Steele inclusive scan over the 1024 partial sums
    for (int off = 1; off < SCAN_T; off <<= 1) {
        int v = (t >= off) ? sums[t - off] : 0;
        __syncthreads();
        sums[t] += v;
        __syncthreads();
    }
    int prefix = (t == 0) ? 0 : sums[t - 1];
    for (int i = lo; i < hi; ++i) {
        row[i] = prefix;
        int d = deg[i];
        inv[i] = 1.0f / fmaxf((float)d, 1.0f);
        prefix += d;
    }
    if (t == SCAN_T - 1) row[N_NODES] = prefix;
}

// ---------------- counting-sort fill: sorted src by dst ----------------
__global__ void fill_kernel(const int* __restrict__ src,
                            const int* __restrict__ dst,
                            const int* __restrict__ row,
                            int* __restrict__ cur,
                            int* __restrict__ sorted) {
    int e = blockIdx.x * blockDim.x + threadIdx.x;
    if (e < N_EDGES) {
        int d = dst[e];
        int pos = atomicAdd(&cur[d], 1);
        sorted[row[d] + pos] = src[e];
    }
}

// ---------------- gather aggregation: one wave per node ----------------
// block = 256 = 4 waves = 4 nodes; lane j owns feature j
__global__ void agg_kernel(const int* __restrict__ row,
                           const int* __restrict__ sorted,
                           const float* __restrict__ inv,
                           const float* __restrict__ x,
                           float* __restrict__ out) {
    int t = threadIdx.x;
    int n = blockIdx.x * 4 + (t >> 6);
    int j = t & 63;
    if (n >= N_NODES) return;
    int beg = row[n], end = row[n + 1];
    float sum = 0.0f;
    int k = beg;
    for (; k + 4 <= end; k += 4) {
        int s0 = sorted[k], s1 = sorted[k + 1], s2 = sorted[k + 2], s3 = sorted[k + 3];
        float v0 = x[(size_t)s0 * DIM + j];
        float v1 = x[(size_t)s1 * DIM + j];
        float v2 = x[(size_t)s2 * DIM + j];
        float v3 = x[(size_t)s3 * DIM + j];
        sum += v0 + v1 + v2 + v3;
    }
    for (; k < end; ++k) sum += x[(size_t)sorted[k] * DIM + j];
    out[(size_t)n * DIM + j] = sum * inv[n];
}

// ---------------- a @ W + b, relu (inv already folded into agg) ----------------
__global__ void linear_relu_kernel(const float* __restrict__ agg,
                                   const float* __restrict__ W,
                                   const float* __restrict__ b,
                                   float* __restrict__ out) {
    __shared__ float Ws[DIM * DIM];
    int t = threadIdx.x;
    for (int k = t; k < DIM * DIM; k += 256) Ws[k] = W[k];
    __syncthreads();
    int n = blockIdx.x * 4 + (t >> 6);
    int j = t & 63;
    if (n < N_NODES) {
        const float* a = agg + (size_t)n * DIM;
        float sum = 0.0f;
#pragma unroll
        for (int d = 0; d < DIM; ++d) sum += a[d] * Ws[d * DIM + j];
        sum += b[j];
        out[(size_t)n * DIM + j] = fmaxf(sum, 0.0f);
    }
}

// ---------------- projection + graph scatter ----------------
__global__ void proj_kernel(const float* __restrict__ x0,
                            const float* __restrict__ x1,
                            const float* __restrict__ Wout,
                            const int* __restrict__ batch,
                            float* __restrict__ gsum,
                            float* __restrict__ gcnt) {
    __shared__ float Ws[DIM * N_CLASS];
    int t = threadIdx.x;
    for (int k = t; k < DIM * N_CLASS; k += 256) Ws[k] = Wout[k];
    __syncthreads();
    int tid = blockIdx.x * blockDim.x + t;
    int n = tid >> 4;
    int c = tid & 15;
    if (n < N_NODES && c < N_CLASS) {
        const float* a = x0 + (size_t)n * DIM;
        const float* bx = x1 + (size_t)n * DIM;
        float sum = 0.0f;
#pragma unroll
        for (int d = 0; d < DIM; ++d) sum += (a[d] + bx[d]) * Ws[d * N_CLASS + c];
        int g = batch[n];
        atomicAdd(&gsum[g * N_CLASS + c], sum * 0.5f);
        if (c == 0) atomicAdd(&gcnt[g], 1.0f);
    }
}

__global__ void finalize_kernel(float* __restrict__ out,
                                const float* __restrict__ gcnt,
                                const float* __restrict__ bout) {
    int i = blockIdx.x * blockDim.x + threadIdx.x;
    if (i < N_GRAPH * N_CLASS) {
        float c = gcnt[i / N_CLASS];
        out[i] = (c > 0.0f) ? (out[i] / c + bout[i % N_CLASS]) : 0.0f;
    }
}

extern "C" void kernel_launch(void* const* d_in, const int* in_sizes, int n_in,
                              void* d_out, int out_size, void* d_ws, size_t ws_size,
                              hipStream_t stream) {
    const float* x    = (const float*)d_in[0];
    const float* W0   = (const float*)d_in[1];
    const float* b0   = (const float*)d_in[2];
    const float* W1   = (const float*)d_in[3];
    const float* b1   = (const float*)d_in[4];
    const float* Wout = (const float*)d_in[5];
    const float* bout = (const float*)d_in[6];
    const int* ei_sc  = (const int*)d_in[7];
    const int* ei_fc  = (const int*)d_in[8];
    const int* batch  = (const int*)d_in[9];

    const int* src_sc = ei_sc;
    const int* dst_sc = ei_sc + N_EDGES;
    const int* src_fc = ei_fc;
    const int* dst_fc = ei_fc + N_EDGES;

    // ---- workspace layout (4-byte elements) ----
    char* ws = (char*)d_ws;
    size_t off = 0;
    auto alloc = [&](size_t elems) { void* p = ws + off; off += elems * 4; return p; };
    float* bufA      = (float*)alloc((size_t)N_NODES * DIM);
    float* bufB      = (float*)alloc((size_t)N_NODES * DIM);
    float* bufC      = (float*)alloc((size_t)N_NODES * DIM);
    float* inv_sc    = (float*)alloc(N_NODES);
    float* inv_fc    = (float*)alloc(N_NODES);
    float* gcnt      = (float*)alloc(N_GRAPH);
    int*   deg_sc    = (int*)alloc(N_NODES);        // also cursor for fill
    int*   deg_fc    = (int*)alloc(N_NODES);
    int*   row_sc    = (int*)alloc(N_NODES + 1);
    int*   row_fc    = (int*)alloc(N_NODES + 1);
    int*   sorted_sc = (int*)alloc(N_EDGES);
    int*   sorted_fc = (int*)alloc(N_EDGES);

    float* gout = (float*)d_out;

    const int BLK = 256;
    dim3 blk(BLK);
    int grid_E   = (N_EDGES + BLK - 1) / BLK;
    int grid_N4  = (N_NODES + 3) / 4;
    int grid_N16 = (N_NODES * 16 + BLK - 1) / BLK;

    // ---- CSR build (once, reused by both layers of each branch) ----
    hipMemsetAsync(deg_sc, 0, 2 * (size_t)N_NODES * sizeof(int), stream);  // deg_sc+deg_fc
    deg_kernel<<<grid_E, blk, 0, stream>>>(dst_sc, dst_fc, deg_sc, deg_fc);
    scan_kernel<<<1, SCAN_T, 0, stream>>>(deg_sc, row_sc, inv_sc);
    scan_kernel<<<1, SCAN_T, 0, stream>>>(deg_fc, row_fc, inv_fc);
    hipMemsetAsync(deg_sc, 0, 2 * (size_t)N_NODES * sizeof(int), stream);  // reuse as cursors
    fill_kernel<<<grid_E, blk, 0, stream>>>(src_sc, dst_sc, row_sc, deg_sc, sorted_sc);
    fill_kernel<<<grid_E, blk, 0, stream>>>(src_fc, dst_fc, row_fc, deg_fc, sorted_fc);

    // ---- branch sc ----
    agg_kernel<<<grid_N4, blk, 0, stream>>>(row_sc, sorted_sc, inv_sc, x, bufA);
    linear_relu_kernel<<<grid_N4, blk, 0, stream>>>(bufA, W0, b0, bufB);
    agg_kernel<<<grid_N4, blk, 0, stream>>>(row_sc, sorted_sc, inv_sc, bufB, bufA);
    linear_relu_kernel<<<grid_N4, blk, 0, stream>>>(bufA, W0 + DIM * DIM, b0 + DIM, bufB);

    // ---- branch fc ----
    agg_kernel<<<grid_N4, blk, 0, stream>>>(row_fc, sorted_fc, inv_fc, x, bufA);
    linear_relu_kernel<<<grid_N4, blk, 0, stream>>>(bufA, W1, b1, bufC);
    agg_kernel<<<grid_N4, blk, 0, stream>>>(row_fc, sorted_fc, inv_fc, bufC, bufA);
    linear_relu_kernel<<<grid_N4, blk, 0, stream>>>(bufA, W1 + DIM * DIM, b1 + DIM, bufC);

    // ---- projection + graph reduce ----
    hipMemsetAsync(gcnt, 0, N_GRAPH * sizeof(float), stream);
    hipMemsetAsync(d_out, 0, (size_t)N_GRAPH * N_CLASS * sizeof(float), stream);
    proj_kernel<<<grid_N16, blk, 0, stream>>>(bufB, bufC, Wout, batch, gout, gcnt);
    finalize_kernel<<<(N_GRAPH * N_CLASS + BLK - 1) / BLK, blk, 0, stream>>>(gout, gcnt, bout);
}

// Round 3
// 411.332 us; speedup vs baseline: 7.4804x; 1.8239x over previous
//
#include <hip/hip_runtime.h>

#define N_NODES 50000
#define N_EDGES 800000
#define DIM 64
#define N_GRAPH 512
#define N_CLASS 10
#define SCHUNK 512
#define NSCB ((N_NODES + SCHUNK - 1) / SCHUNK)   // 98 blocks per branch

// ---------------- integer degree (both branches) ----------------
__global__ void deg_kernel(const int* __restrict__ dst_sc,
                           const int* __restrict__ dst_fc,
                           int* __restrict__ deg_sc,
                           int* __restrict__ deg_fc) {
    int i = blockIdx.x * blockDim.x + threadIdx.x;
    if (i < N_EDGES) {
        atomicAdd(&deg_sc[dst_sc[i]], 1);
        atomicAdd(&deg_fc[dst_fc[i]], 1);
    }
}

// ---------------- hierarchical scan: A = per-block sums ----------------
__global__ void scanA_kernel(const int* __restrict__ deg_sc,
                             const int* __restrict__ deg_fc,
                             int* __restrict__ partial) {
    const int* deg = blockIdx.y ? deg_fc : deg_sc;
    int base = blockIdx.x * SCHUNK;
    int t = threadIdx.x;
    int s = 0;
    int i0 = base + t, i1 = base + t + 256;
    if (i0 < N_NODES) s += deg[i0];
    if (i1 < N_NODES) s += deg[i1];
    __shared__ int red[256];
    red[t] = s;
    __syncthreads();
    for (int off = 128; off > 0; off >>= 1) {
        if (t < off) red[t] += red[t + off];
        __syncthreads();
    }
    if (t == 0) partial[blockIdx.y * NSCB + blockIdx.x] = red[0];
}

// ---------------- B: exclusive scan of the 2x98 partials ----------------
__global__ void scanB_kernel(int* __restrict__ partial) {
    __shared__ int s[2 * NSCB];
    int t = threadIdx.x;
    for (int k = t; k < 2 * NSCB; k += blockDim.x) s[k] = partial[k];
    __syncthreads();
    if (t < 2) {
        int* p = s + t * NSCB;
        int run = 0;
        for (int i = 0; i < NSCB; ++i) { int v = p[i]; p[i] = run; run += v; }
    }
    __syncthreads();
    for (int k = t; k < 2 * NSCB; k += blockDim.x) partial[k] = s[k];
}

// ---------------- C: per-block local scan -> row offsets + inv ----------------
__global__ void scanC_kernel(const int* __restrict__ deg_sc,
                             const int* __restrict__ deg_fc,
                             const int* __restrict__ partial,
                             int* __restrict__ row_sc, int* __restrict__ row_fc,
                             float* __restrict__ inv_sc, float* __restrict__ inv_fc) {
    const int* deg = blockIdx.y ? deg_fc : deg_sc;
    int* row = blockIdx.y ? row_fc : row_sc;
    float* inv = blockIdx.y ? inv_fc : inv_sc;
    int base = blockIdx.x * SCHUNK;
    int t = threadIdx.x;
    int i0 = base + 2 * t, i1 = i0 + 1;
    int d0 = (i0 < N_NODES) ? deg[i0] : 0;
    int d1 = (i1 < N_NODES) ? deg[i1] : 0;
    __shared__ int s[256];
    s[t] = d0 + d1;
    __syncthreads();
    for (int off = 1; off < 256; off <<= 1) {
        int v = (t >= off) ? s[t - off] : 0;
        __syncthreads();
        s[t] += v;
        __syncthreads();
    }
    int pre = (t == 0) ? 0 : s[t - 1];
    int blockbase = partial[blockIdx.y * NSCB + blockIdx.x];
    int r0 = blockbase + pre;
    if (i0 < N_NODES) { row[i0] = r0;      inv[i0] = 1.0f / fmaxf((float)d0, 1.0f); }
    if (i1 < N_NODES) { row[i1] = r0 + d0; inv[i1] = 1.0f / fmaxf((float)d1, 1.0f); }
    if (blockIdx.x == 0 && t == 0) row[N_NODES] = N_EDGES;  // every edge lands in [0,N)
}

// ---------------- counting-sort fill (both branches via grid.y) ----------------
__global__ void fill_kernel(const int* __restrict__ src_sc, const int* __restrict__ dst_sc,
                            const int* __restrict__ src_fc, const int* __restrict__ dst_fc,
                            const int* __restrict__ row_sc, const int* __restrict__ row_fc,
                            int* __restrict__ cur_sc, int* __restrict__ cur_fc,
                            int* __restrict__ sorted_sc, int* __restrict__ sorted_fc) {
    int e = blockIdx.x * blockDim.x + threadIdx.x;
    if (e >= N_EDGES) return;
    const int *src, *dst, *row;
    int *cur, *sorted;
    if (blockIdx.y == 0) { src = src_sc; dst = dst_sc; row = row_sc; cur = cur_sc; sorted = sorted_sc; }
    else                 { src = src_fc; dst = dst_fc; row = row_fc; cur = cur_fc; sorted = sorted_fc; }
    int d = dst[e];
    int pos = atomicAdd(&cur[d], 1);
    sorted[row[d] + pos] = src[e];
}

// ---------------- fused gather-aggregate + linear + relu ----------------
// block = 256 threads = 4 waves = 4 nodes; lane j owns feature j.
// blockIdx.y selects branch (a or b pointer set).
__global__ void layer_kernel(const int* __restrict__ row_a, const int* __restrict__ sorted_a,
                             const float* __restrict__ inv_a, const float* __restrict__ in_a,
                             const float* __restrict__ Wa, const float* __restrict__ ba,
                             float* __restrict__ out_a,
                             const int* __restrict__ row_b, const int* __restrict__ sorted_b,
                             const float* __restrict__ inv_b, const float* __restrict__ in_b,
                             const float* __restrict__ Wb, const float* __restrict__ bb,
                             float* __restrict__ out_b) {
    const int* row;  const int* sorted; const float* inv; const float* in;
    const float* W;  const float* bias; float* out;
    if (blockIdx.y == 0) { row = row_a; sorted = sorted_a; inv = inv_a; in = in_a; W = Wa; bias = ba; out = out_a; }
    else                 { row = row_b; sorted = sorted_b; inv = inv_b; in = in_b; W = Wb; bias = bb; out = out_b; }

    __shared__ float Ws[DIM * DIM];
    __shared__ float As[4][DIM];
    int t = threadIdx.x;
    for (int k = t; k < DIM * DIM; k += 256) Ws[k] = W[k];

    int w = t >> 6, j = t & 63;
    int n = blockIdx.x * 4 + w;
    if (n < N_NODES) {
        int beg = row[n], end = row[n + 1];
        float sum = 0.0f;
        int k = beg;
        for (; k + 4 <= end; k += 4) {
            int s0 = sorted[k], s1 = sorted[k + 1], s2 = sorted[k + 2], s3 = sorted[k + 3];
            sum += in[(size_t)s0 * DIM + j] + in[(size_t)s1 * DIM + j]
                 + in[(size_t)s2 * DIM + j] + in[(size_t)s3 * DIM + j];
        }
        for (; k < end; ++k) sum += in[(size_t)sorted[k] * DIM + j];
        As[w][j] = sum * inv[n];
    }
    __syncthreads();
    if (n < N_NODES) {
        float acc = 0.0f;
#pragma unroll
        for (int d = 0; d < DIM; ++d) acc += As[w][d] * Ws[d * DIM + j];
        out[(size_t)n * DIM + j] = fmaxf(acc + bias[j], 0.0f);
    }
}

// ---------------- per-graph projection (batch_idx sorted -> contiguous ranges) ----------------
__global__ void graph_proj_kernel(const float* __restrict__ x0, const float* __restrict__ x1,
                                  const float* __restrict__ Wout, const float* __restrict__ bout,
                                  const int* __restrict__ batch, float* __restrict__ out) {
    int g = blockIdx.x;
    __shared__ int bounds[2];
    __shared__ float hs[4][DIM];
    int t = threadIdx.x;
    if (t < 2) {
        int target = g + t;           // lower_bound(batch, g) and lower_bound(batch, g+1)
        int lo = 0, hi = N_NODES;
        while (lo < hi) { int mid = (lo + hi) >> 1; if (batch[mid] < target) lo = mid + 1; else hi = mid; }
        bounds[t] = lo;
    }
    __syncthreads();
    int beg = bounds[0], end = bounds[1];
    int w = t >> 6, j = t & 63;
    float s = 0.0f;
    for (int n = beg + w; n < end; n += 4)
        s += x0[(size_t)n * DIM + j] + x1[(size_t)n * DIM + j];
    hs[w][j] = s;
    __syncthreads();
    if (t < DIM) hs[0][t] = (hs[0][t] + hs[1][t] + hs[2][t] + hs[3][t]) * 0.5f;
    __syncthreads();
    if (t < N_CLASS) {
        int cnt = end - beg;
        float acc = 0.0f;
#pragma unroll
        for (int d = 0; d < DIM; ++d) acc += hs[0][d] * Wout[d * N_CLASS + t];
        out[g * N_CLASS + t] = (cnt > 0) ? (acc / (float)cnt + bout[t]) : 0.0f;
    }
}

extern "C" void kernel_launch(void* const* d_in, const int* in_sizes, int n_in,
                              void* d_out, int out_size, void* d_ws, size_t ws_size,
                              hipStream_t stream) {
    const float* x    = (const float*)d_in[0];
    const float* W0   = (const float*)d_in[1];
    const float* b0   = (const float*)d_in[2];
    const float* W1   = (const float*)d_in[3];
    const float* b1   = (const float*)d_in[4];
    const float* Wout = (const float*)d_in[5];
    const float* bout = (const float*)d_in[6];
    const int* ei_sc  = (const int*)d_in[7];
    const int* ei_fc  = (const int*)d_in[8];
    const int* batch  = (const int*)d_in[9];

    const int* src_sc = ei_sc;
    const int* dst_sc = ei_sc + N_EDGES;
    const int* src_fc = ei_fc;
    const int* dst_fc = ei_fc + N_EDGES;

    // ---- workspace layout (4-byte elements) ----
    char* ws = (char*)d_ws;
    size_t off = 0;
    auto alloc = [&](size_t elems) { void* p = ws + off; off += elems * 4; return p; };
    float* bufA      = (float*)alloc((size_t)N_NODES * DIM);   // sc layer-1 out
    float* bufB      = (float*)alloc((size_t)N_NODES * DIM);   // sc hidden -> fc layer-1 out
    float* bufC      = (float*)alloc((size_t)N_NODES * DIM);   // fc hidden
    float* inv_sc    = (float*)alloc(N_NODES);
    float* inv_fc    = (float*)alloc(N_NODES);
    int*   deg_sc    = (int*)alloc(N_NODES);                   // also fill cursor
    int*   deg_fc    = (int*)alloc(N_NODES);
    int*   row_sc    = (int*)alloc(N_NODES + 1);
    int*   row_fc    = (int*)alloc(N_NODES + 1);
    int*   partial   = (int*)alloc(2 * NSCB);
    int*   sorted_sc = (int*)alloc(N_EDGES);
    int*   sorted_fc = (int*)alloc(N_EDGES);

    const int BLK = 256;
    dim3 blk(BLK);
    int grid_E  = (N_EDGES + BLK - 1) / BLK;
    int grid_N4 = (N_NODES + 3) / 4;

    // ---- CSR build ----
    hipMemsetAsync(deg_sc, 0, 2 * (size_t)N_NODES * sizeof(int), stream);
    deg_kernel<<<grid_E, blk, 0, stream>>>(dst_sc, dst_fc, deg_sc, deg_fc);
    scanA_kernel<<<dim3(NSCB, 2), blk, 0, stream>>>(deg_sc, deg_fc, partial);
    scanB_kernel<<<1, 64, 0, stream>>>(partial);
    scanC_kernel<<<dim3(NSCB, 2), blk, 0, stream>>>(deg_sc, deg_fc, partial,
                                                    row_sc, row_fc, inv_sc, inv_fc);
    hipMemsetAsync(deg_sc, 0, 2 * (size_t)N_NODES * sizeof(int), stream);  // cursors
    fill_kernel<<<dim3(grid_E, 2), blk, 0, stream>>>(src_sc, dst_sc, src_fc, dst_fc,
                                                     row_sc, row_fc, deg_sc, deg_fc,
                                                     sorted_sc, sorted_fc);

    // ---- layer 0: both branches in one launch (x -> bufB, bufC) ----
    layer_kernel<<<dim3(grid_N4, 2), blk, 0, stream>>>(
        row_sc, sorted_sc, inv_sc, x, W0, b0, bufB,
        row_fc, sorted_fc, inv_fc, x, W1, b1, bufC);

    // ---- layer 1: sc (bufB -> bufA), then fc (bufC -> bufB) ----
    layer_kernel<<<dim3(grid_N4, 1), blk, 0, stream>>>(
        row_sc, sorted_sc, inv_sc, bufB, W0 + DIM * DIM, b0 + DIM, bufA,
        row_sc, sorted_sc, inv_sc, bufB, W0 + DIM * DIM, b0 + DIM, bufA);
    layer_kernel<<<dim3(grid_N4, 1), blk, 0, stream>>>(
        row_fc, sorted_fc, inv_fc, bufC, W1 + DIM * DIM, b1 + DIM, bufB,
        row_fc, sorted_fc, inv_fc, bufC, W1 + DIM * DIM, b1 + DIM, bufB);

    // ---- per-graph projection (no atomics, no finalize) ----
    graph_proj_kernel<<<N_GRAPH, blk, 0, stream>>>(bufA, bufB, Wout, bout, batch,
                                                   (float*)d_out);
}

// Round 4
// 398.216 us; speedup vs baseline: 7.7268x; 1.0329x over previous
//
#include <hip/hip_runtime.h>

#define N_NODES 50000
#define N_EDGES 800000
#define DIM 64
#define N_GRAPH 512
#define N_CLASS 10
#define SCHUNK 512
#define NSCB ((N_NODES + SCHUNK - 1) / SCHUNK)   // 98 blocks per branch
#define NPB 8                                     // nodes per block in layer kernel
#define LBLK (NPB * 64)                           // 512 threads

// ---------------- integer degree (both branches) ----------------
__global__ void deg_kernel(const int* __restrict__ dst_sc,
                           const int* __restrict__ dst_fc,
                           int* __restrict__ deg_sc,
                           int* __restrict__ deg_fc) {
    int i = blockIdx.x * blockDim.x + threadIdx.x;
    if (i < N_EDGES) {
        atomicAdd(&deg_sc[dst_sc[i]], 1);
        atomicAdd(&deg_fc[dst_fc[i]], 1);
    }
}

// ---------------- hierarchical scan: A = per-block sums ----------------
__global__ void scanA_kernel(const int* __restrict__ deg_sc,
                             const int* __restrict__ deg_fc,
                             int* __restrict__ partial) {
    const int* deg = blockIdx.y ? deg_fc : deg_sc;
    int base = blockIdx.x * SCHUNK;
    int t = threadIdx.x;
    int s = 0;
    int i0 = base + t, i1 = base + t + 256;
    if (i0 < N_NODES) s += deg[i0];
    if (i1 < N_NODES) s += deg[i1];
    __shared__ int red[256];
    red[t] = s;
    __syncthreads();
    for (int off = 128; off > 0; off >>= 1) {
        if (t < off) red[t] += red[t + off];
        __syncthreads();
    }
    if (t == 0) partial[blockIdx.y * NSCB + blockIdx.x] = red[0];
}

// ---------------- B: exclusive scan of the 2x98 partials ----------------
__global__ void scanB_kernel(int* __restrict__ partial) {
    __shared__ int s[2 * NSCB];
    int t = threadIdx.x;
    for (int k = t; k < 2 * NSCB; k += blockDim.x) s[k] = partial[k];
    __syncthreads();
    if (t < 2) {
        int* p = s + t * NSCB;
        int run = 0;
        for (int i = 0; i < NSCB; ++i) { int v = p[i]; p[i] = run; run += v; }
    }
    __syncthreads();
    for (int k = t; k < 2 * NSCB; k += blockDim.x) partial[k] = s[k];
}

// ---------------- C: per-block local scan -> row offsets + inv ----------------
__global__ void scanC_kernel(const int* __restrict__ deg_sc,
                             const int* __restrict__ deg_fc,
                             const int* __restrict__ partial,
                             int* __restrict__ row_sc, int* __restrict__ row_fc,
                             float* __restrict__ inv_sc, float* __restrict__ inv_fc) {
    const int* deg = blockIdx.y ? deg_fc : deg_sc;
    int* row = blockIdx.y ? row_fc : row_sc;
    float* inv = blockIdx.y ? inv_fc : inv_sc;
    int base = blockIdx.x * SCHUNK;
    int t = threadIdx.x;
    int i0 = base + 2 * t, i1 = i0 + 1;
    int d0 = (i0 < N_NODES) ? deg[i0] : 0;
    int d1 = (i1 < N_NODES) ? deg[i1] : 0;
    __shared__ int s[256];
    s[t] = d0 + d1;
    __syncthreads();
    for (int off = 1; off < 256; off <<= 1) {
        int v = (t >= off) ? s[t - off] : 0;
        __syncthreads();
        s[t] += v;
        __syncthreads();
    }
    int pre = (t == 0) ? 0 : s[t - 1];
    int blockbase = partial[blockIdx.y * NSCB + blockIdx.x];
    int r0 = blockbase + pre;
    if (i0 < N_NODES) { row[i0] = r0;      inv[i0] = 1.0f / fmaxf((float)d0, 1.0f); }
    if (i1 < N_NODES) { row[i1] = r0 + d0; inv[i1] = 1.0f / fmaxf((float)d1, 1.0f); }
    if (blockIdx.x == 0 && t == 0) row[N_NODES] = N_EDGES;  // every edge lands in [0,N)
}

// ---------------- counting-sort fill (both branches via grid.y) ----------------
__global__ void fill_kernel(const int* __restrict__ src_sc, const int* __restrict__ dst_sc,
                            const int* __restrict__ src_fc, const int* __restrict__ dst_fc,
                            const int* __restrict__ row_sc, const int* __restrict__ row_fc,
                            int* __restrict__ cur_sc, int* __restrict__ cur_fc,
                            int* __restrict__ sorted_sc, int* __restrict__ sorted_fc) {
    int e = blockIdx.x * blockDim.x + threadIdx.x;
    if (e >= N_EDGES) return;
    const int *src, *dst, *row;
    int *cur, *sorted;
    if (blockIdx.y == 0) { src = src_sc; dst = dst_sc; row = row_sc; cur = cur_sc; sorted = sorted_sc; }
    else                 { src = src_fc; dst = dst_fc; row = row_fc; cur = cur_fc; sorted = sorted_fc; }
    int d = dst[e];
    int pos = atomicAdd(&cur[d], 1);
    sorted[row[d] + pos] = src[e];
}

// ---------------- fused gather-aggregate + linear + relu ----------------
// block = 512 threads = 8 waves = 8 nodes; lane j owns feature j.
// blockIdx.y selects branch (a or b pointer set).
__global__ void __launch_bounds__(LBLK)
layer_kernel(const int* __restrict__ row_a, const int* __restrict__ sorted_a,
             const float* __restrict__ inv_a, const float* __restrict__ in_a,
             const float* __restrict__ Wa, const float* __restrict__ ba,
             float* __restrict__ out_a,
             const int* __restrict__ row_b, const int* __restrict__ sorted_b,
             const float* __restrict__ inv_b, const float* __restrict__ in_b,
             const float* __restrict__ Wb, const float* __restrict__ bb,
             float* __restrict__ out_b) {
    const int* row;  const int* sorted; const float* inv; const float* in;
    const float* W;  const float* bias; float* out;
    if (blockIdx.y == 0) { row = row_a; sorted = sorted_a; inv = inv_a; in = in_a; W = Wa; bias = ba; out = out_a; }
    else                 { row = row_b; sorted = sorted_b; inv = inv_b; in = in_b; W = Wb; bias = bb; out = out_b; }

    __shared__ float Ws[DIM * DIM];
    __shared__ float As[NPB][DIM];
    int t = threadIdx.x;
    for (int k = t; k < DIM * DIM; k += LBLK) Ws[k] = W[k];

    int w = t >> 6, j = t & 63;
    int n = blockIdx.x * NPB + w;
    if (n < N_NODES) {
        int beg = row[n], end = row[n + 1];
        float sum = 0.0f;
        int k = beg;
        // 8 loads in flight for latency hiding
        for (; k + 8 <= end; k += 8) {
            int s0 = sorted[k],     s1 = sorted[k + 1], s2 = sorted[k + 2], s3 = sorted[k + 3];
            int s4 = sorted[k + 4], s5 = sorted[k + 5], s6 = sorted[k + 6], s7 = sorted[k + 7];
            float v0 = in[(size_t)s0 * DIM + j], v1 = in[(size_t)s1 * DIM + j];
            float v2 = in[(size_t)s2 * DIM + j], v3 = in[(size_t)s3 * DIM + j];
            float v4 = in[(size_t)s4 * DIM + j], v5 = in[(size_t)s5 * DIM + j];
            float v6 = in[(size_t)s6 * DIM + j], v7 = in[(size_t)s7 * DIM + j];
            sum += ((v0 + v1) + (v2 + v3)) + ((v4 + v5) + (v6 + v7));
        }
        for (; k < end; ++k) sum += in[(size_t)sorted[k] * DIM + j];
        As[w][j] = sum * inv[n];
    }
    __syncthreads();
    if (n < N_NODES) {
        float acc = 0.0f;
#pragma unroll
        for (int d = 0; d < DIM; ++d) acc += As[w][d] * Ws[d * DIM + j];
        out[(size_t)n * DIM + j] = fmaxf(acc + bias[j], 0.0f);
    }
}

// ---------------- per-graph projection (batch_idx sorted -> contiguous ranges) ----------------
__global__ void graph_proj_kernel(const float* __restrict__ x0, const float* __restrict__ x1,
                                  const float* __restrict__ Wout, const float* __restrict__ bout,
                                  const int* __restrict__ batch, float* __restrict__ out) {
    int g = blockIdx.x;
    __shared__ int bounds[2];
    __shared__ float hs[4][DIM];
    int t = threadIdx.x;
    if (t < 2) {
        int target = g + t;           // lower_bound(batch, g) and lower_bound(batch, g+1)
        int lo = 0, hi = N_NODES;
        while (lo < hi) { int mid = (lo + hi) >> 1; if (batch[mid] < target) lo = mid + 1; else hi = mid; }
        bounds[t] = lo;
    }
    __syncthreads();
    int beg = bounds[0], end = bounds[1];
    int w = t >> 6, j = t & 63;
    float s = 0.0f;
    for (int n = beg + w; n < end; n += 4)
        s += x0[(size_t)n * DIM + j] + x1[(size_t)n * DIM + j];
    hs[w][j] = s;
    __syncthreads();
    if (t < DIM) hs[0][t] = (hs[0][t] + hs[1][t] + hs[2][t] + hs[3][t]) * 0.5f;
    __syncthreads();
    if (t < N_CLASS) {
        int cnt = end - beg;
        float acc = 0.0f;
#pragma unroll
        for (int d = 0; d < DIM; ++d) acc += hs[0][d] * Wout[d * N_CLASS + t];
        out[g * N_CLASS + t] = (cnt > 0) ? (acc / (float)cnt + bout[t]) : 0.0f;
    }
}

extern "C" void kernel_launch(void* const* d_in, const int* in_sizes, int n_in,
                              void* d_out, int out_size, void* d_ws, size_t ws_size,
                              hipStream_t stream) {
    const float* x    = (const float*)d_in[0];
    const float* W0   = (const float*)d_in[1];
    const float* b0   = (const float*)d_in[2];
    const float* W1   = (const float*)d_in[3];
    const float* b1   = (const float*)d_in[4];
    const float* Wout = (const float*)d_in[5];
    const float* bout = (const float*)d_in[6];
    const int* ei_sc  = (const int*)d_in[7];
    const int* ei_fc  = (const int*)d_in[8];
    const int* batch  = (const int*)d_in[9];

    const int* src_sc = ei_sc;
    const int* dst_sc = ei_sc + N_EDGES;
    const int* src_fc = ei_fc;
    const int* dst_fc = ei_fc + N_EDGES;

    // ---- workspace layout (4-byte elements) ----
    char* ws = (char*)d_ws;
    size_t off = 0;
    auto alloc = [&](size_t elems) { void* p = ws + off; off += elems * 4; return p; };
    float* bufA      = (float*)alloc((size_t)N_NODES * DIM);   // sc layer-1 out
    float* bufB      = (float*)alloc((size_t)N_NODES * DIM);   // sc hidden
    float* bufC      = (float*)alloc((size_t)N_NODES * DIM);   // fc hidden
    float* inv_sc    = (float*)alloc(N_NODES);
    float* inv_fc    = (float*)alloc(N_NODES);
    int*   deg_sc    = (int*)alloc(N_NODES);                   // also fill cursor
    int*   deg_fc    = (int*)alloc(N_NODES);
    int*   row_sc    = (int*)alloc(N_NODES + 1);
    int*   row_fc    = (int*)alloc(N_NODES + 1);
    int*   partial   = (int*)alloc(2 * NSCB);
    int*   sorted_sc = (int*)alloc(N_EDGES);
    int*   sorted_fc = (int*)alloc(N_EDGES);
    size_t base_off  = off;
    float* bufD      = (float*)alloc((size_t)N_NODES * DIM);   // fc layer-1 out (optional)
    bool have_bufD = (off <= ws_size);

    const int BLK = 256;
    dim3 blk(BLK);
    int grid_E  = (N_EDGES + BLK - 1) / BLK;
    int grid_N8 = (N_NODES + NPB - 1) / NPB;

    // ---- CSR build ----
    hipMemsetAsync(deg_sc, 0, 2 * (size_t)N_NODES * sizeof(int), stream);
    deg_kernel<<<grid_E, blk, 0, stream>>>(dst_sc, dst_fc, deg_sc, deg_fc);
    scanA_kernel<<<dim3(NSCB, 2), blk, 0, stream>>>(deg_sc, deg_fc, partial);
    scanB_kernel<<<1, 64, 0, stream>>>(partial);
    scanC_kernel<<<dim3(NSCB, 2), blk, 0, stream>>>(deg_sc, deg_fc, partial,
                                                    row_sc, row_fc, inv_sc, inv_fc);
    hipMemsetAsync(deg_sc, 0, 2 * (size_t)N_NODES * sizeof(int), stream);  // cursors
    fill_kernel<<<dim3(grid_E, 2), blk, 0, stream>>>(src_sc, dst_sc, src_fc, dst_fc,
                                                     row_sc, row_fc, deg_sc, deg_fc,
                                                     sorted_sc, sorted_fc);

    // ---- layer 0: both branches in one launch (x -> bufB, bufC) ----
    layer_kernel<<<dim3(grid_N8, 2), LBLK, 0, stream>>>(
        row_sc, sorted_sc, inv_sc, x, W0, b0, bufB,
        row_fc, sorted_fc, inv_fc, x, W1, b1, bufC);

    float* fc_out;
    if (have_bufD) {
        // ---- layer 1: both branches in one launch (bufB->bufA, bufC->bufD) ----
        layer_kernel<<<dim3(grid_N8, 2), LBLK, 0, stream>>>(
            row_sc, sorted_sc, inv_sc, bufB, W0 + DIM * DIM, b0 + DIM, bufA,
            row_fc, sorted_fc, inv_fc, bufC, W1 + DIM * DIM, b1 + DIM, bufD);
        fc_out = bufD;
    } else {
        // fallback: serialize (fc overwrites bufB after sc consumed it)
        layer_kernel<<<dim3(grid_N8, 1), LBLK, 0, stream>>>(
            row_sc, sorted_sc, inv_sc, bufB, W0 + DIM * DIM, b0 + DIM, bufA,
            row_sc, sorted_sc, inv_sc, bufB, W0 + DIM * DIM, b0 + DIM, bufA);
        layer_kernel<<<dim3(grid_N8, 1), LBLK, 0, stream>>>(
            row_fc, sorted_fc, inv_fc, bufC, W1 + DIM * DIM, b1 + DIM, bufB,
            row_fc, sorted_fc, inv_fc, bufC, W1 + DIM * DIM, b1 + DIM, bufB);
        fc_out = bufB;
    }
    (void)base_off;

    // ---- per-graph projection (no atomics, no finalize) ----
    graph_proj_kernel<<<N_GRAPH, 256, 0, stream>>>(bufA, fc_out, Wout, bout, batch,
                                                   (float*)d_out);
}

// Round 5
// 348.013 us; speedup vs baseline: 8.8415x; 1.1443x over previous
//
#include <hip/hip_runtime.h>

#define N_NODES 50000
#define N_EDGES 800000
#define DIM 64
#define N_GRAPH 512
#define N_CLASS 10
#define SCHUNK 512
#define NSCB ((N_NODES + SCHUNK - 1) / SCHUNK)   // 98 blocks per branch
#define NPB 8                                     // nodes per block in layer kernel
#define LBLK (NPB * 64)                           // 512 threads

// ---------------- integer degree (both branches) ----------------
__global__ void deg_kernel(const int* __restrict__ dst_sc,
                           const int* __restrict__ dst_fc,
                           int* __restrict__ deg_sc,
                           int* __restrict__ deg_fc) {
    int i = blockIdx.x * blockDim.x + threadIdx.x;
    if (i < N_EDGES) {
        atomicAdd(&deg_sc[dst_sc[i]], 1);
        atomicAdd(&deg_fc[dst_fc[i]], 1);
    }
}

// ---------------- hierarchical scan: A = per-block sums ----------------
__global__ void scanA_kernel(const int* __restrict__ deg_sc,
                             const int* __restrict__ deg_fc,
                             int* __restrict__ partial) {
    const int* deg = blockIdx.y ? deg_fc : deg_sc;
    int base = blockIdx.x * SCHUNK;
    int t = threadIdx.x;
    int s = 0;
    int i0 = base + t, i1 = base + t + 256;
    if (i0 < N_NODES) s += deg[i0];
    if (i1 < N_NODES) s += deg[i1];
    __shared__ int red[256];
    red[t] = s;
    __syncthreads();
    for (int off = 128; off > 0; off >>= 1) {
        if (t < off) red[t] += red[t + off];
        __syncthreads();
    }
    if (t == 0) partial[blockIdx.y * NSCB + blockIdx.x] = red[0];
}

// ---------------- B: exclusive scan of the 2x98 partials ----------------
__global__ void scanB_kernel(int* __restrict__ partial) {
    __shared__ int s[2 * NSCB];
    int t = threadIdx.x;
    for (int k = t; k < 2 * NSCB; k += blockDim.x) s[k] = partial[k];
    __syncthreads();
    if (t < 2) {
        int* p = s + t * NSCB;
        int run = 0;
        for (int i = 0; i < NSCB; ++i) { int v = p[i]; p[i] = run; run += v; }
    }
    __syncthreads();
    for (int k = t; k < 2 * NSCB; k += blockDim.x) partial[k] = s[k];
}

// ---------------- C: per-block local scan -> row offsets + inv ----------------
__global__ void scanC_kernel(const int* __restrict__ deg_sc,
                             const int* __restrict__ deg_fc,
                             const int* __restrict__ partial,
                             int* __restrict__ row_sc, int* __restrict__ row_fc,
                             float* __restrict__ inv_sc, float* __restrict__ inv_fc) {
    const int* deg = blockIdx.y ? deg_fc : deg_sc;
    int* row = blockIdx.y ? row_fc : row_sc;
    float* inv = blockIdx.y ? inv_fc : inv_sc;
    int base = blockIdx.x * SCHUNK;
    int t = threadIdx.x;
    int i0 = base + 2 * t, i1 = i0 + 1;
    int d0 = (i0 < N_NODES) ? deg[i0] : 0;
    int d1 = (i1 < N_NODES) ? deg[i1] : 0;
    __shared__ int s[256];
    s[t] = d0 + d1;
    __syncthreads();
    for (int off = 1; off < 256; off <<= 1) {
        int v = (t >= off) ? s[t - off] : 0;
        __syncthreads();
        s[t] += v;
        __syncthreads();
    }
    int pre = (t == 0) ? 0 : s[t - 1];
    int blockbase = partial[blockIdx.y * NSCB + blockIdx.x];
    int r0 = blockbase + pre;
    if (i0 < N_NODES) { row[i0] = r0;      inv[i0] = 1.0f / fmaxf((float)d0, 1.0f); }
    if (i1 < N_NODES) { row[i1] = r0 + d0; inv[i1] = 1.0f / fmaxf((float)d1, 1.0f); }
    if (blockIdx.x == 0 && t == 0) row[N_NODES] = N_EDGES;  // every edge lands in [0,N)
}

// ---------------- counting-sort fill (both branches via grid.y) ----------------
__global__ void fill_kernel(const int* __restrict__ src_sc, const int* __restrict__ dst_sc,
                            const int* __restrict__ src_fc, const int* __restrict__ dst_fc,
                            const int* __restrict__ row_sc, const int* __restrict__ row_fc,
                            int* __restrict__ cur_sc, int* __restrict__ cur_fc,
                            int* __restrict__ sorted_sc, int* __restrict__ sorted_fc) {
    int e = blockIdx.x * blockDim.x + threadIdx.x;
    if (e >= N_EDGES) return;
    const int *src, *dst, *row;
    int *cur, *sorted;
    if (blockIdx.y == 0) { src = src_sc; dst = dst_sc; row = row_sc; cur = cur_sc; sorted = sorted_sc; }
    else                 { src = src_fc; dst = dst_fc; row = row_fc; cur = cur_fc; sorted = sorted_fc; }
    int d = dst[e];
    int pos = atomicAdd(&cur[d], 1);
    sorted[row[d] + pos] = src[e];
}

// ---------------- fused gather-aggregate + linear + relu ----------------
// block = 512 threads = 8 waves = 8 nodes.
// Within a wave: 4 edge-groups x 16 lanes; lane covers feature chunk c..c+3 via
// float4 loads, so ONE load instruction fetches four full 256B rows.
// blockIdx.y selects branch (a or b pointer set).
__global__ void __launch_bounds__(LBLK)
layer_kernel(const int* __restrict__ row_a, const int* __restrict__ sorted_a,
             const float* __restrict__ inv_a, const float* __restrict__ in_a,
             const float* __restrict__ Wa, const float* __restrict__ ba,
             float* __restrict__ out_a,
             const int* __restrict__ row_b, const int* __restrict__ sorted_b,
             const float* __restrict__ inv_b, const float* __restrict__ in_b,
             const float* __restrict__ Wb, const float* __restrict__ bb,
             float* __restrict__ out_b) {
    const int* row;  const int* sorted; const float* inv; const float* in;
    const float* W;  const float* bias; float* out;
    if (blockIdx.y == 0) { row = row_a; sorted = sorted_a; inv = inv_a; in = in_a; W = Wa; bias = ba; out = out_a; }
    else                 { row = row_b; sorted = sorted_b; inv = inv_b; in = in_b; W = Wb; bias = bb; out = out_b; }

    __shared__ float Ws[DIM * DIM];
    __shared__ float As[NPB][DIM];
    int t = threadIdx.x;
    for (int k = t; k < DIM * DIM; k += LBLK) Ws[k] = W[k];

    int w = t >> 6, lane = t & 63;
    int eg = lane >> 4;            // edge slot within group-of-4
    int c  = (lane & 15) << 2;     // feature chunk base
    int n = blockIdx.x * NPB + w;
    if (n < N_NODES) {
        int beg = row[n], end = row[n + 1];
        float iv = inv[n];
        float ax = 0.f, ay = 0.f, az = 0.f, aw = 0.f;
        int k = beg;
        for (; k + 8 <= end; k += 8) {       // 8 edges per wave-iteration, 2 float4 in flight
            int s0 = sorted[k + eg];
            int s1 = sorted[k + 4 + eg];
            const float4 v0 = *(const float4*)(in + (size_t)s0 * DIM + c);
            const float4 v1 = *(const float4*)(in + (size_t)s1 * DIM + c);
            ax += v0.x + v1.x; ay += v0.y + v1.y;
            az += v0.z + v1.z; aw += v0.w + v1.w;
        }
        // tail (up to 7 edges): two predicated group-loads
        int k0 = k + eg;
        if (k0 < end) {
            const float4 v = *(const float4*)(in + (size_t)sorted[k0] * DIM + c);
            ax += v.x; ay += v.y; az += v.z; aw += v.w;
        }
        int k1 = k + 4 + eg;
        if (k1 < end) {
            const float4 v = *(const float4*)(in + (size_t)sorted[k1] * DIM + c);
            ax += v.x; ay += v.y; az += v.z; aw += v.w;
        }
        // reduce across the 4 edge-groups (lane ^ 16, lane ^ 32)
        ax += __shfl_xor(ax, 16, 64); ay += __shfl_xor(ay, 16, 64);
        az += __shfl_xor(az, 16, 64); aw += __shfl_xor(aw, 16, 64);
        ax += __shfl_xor(ax, 32, 64); ay += __shfl_xor(ay, 32, 64);
        az += __shfl_xor(az, 32, 64); aw += __shfl_xor(aw, 32, 64);
        if (eg == 0) {
            float4 r = make_float4(ax * iv, ay * iv, az * iv, aw * iv);
            *(float4*)&As[w][c] = r;
        }
    }
    __syncthreads();
    if (n < N_NODES) {
        int j = lane;
        float acc = 0.0f;
#pragma unroll
        for (int d = 0; d < DIM; ++d) acc += As[w][d] * Ws[d * DIM + j];
        out[(size_t)n * DIM + j] = fmaxf(acc + bias[j], 0.0f);
    }
}

// ---------------- per-graph projection (batch_idx sorted -> contiguous ranges) ----------------
__global__ void graph_proj_kernel(const float* __restrict__ x0, const float* __restrict__ x1,
                                  const float* __restrict__ Wout, const float* __restrict__ bout,
                                  const int* __restrict__ batch, float* __restrict__ out) {
    int g = blockIdx.x;
    __shared__ int bounds[2];
    __shared__ float hs[4][DIM];
    int t = threadIdx.x;
    if (t < 2) {
        int target = g + t;           // lower_bound(batch, g) and lower_bound(batch, g+1)
        int lo = 0, hi = N_NODES;
        while (lo < hi) { int mid = (lo + hi) >> 1; if (batch[mid] < target) lo = mid + 1; else hi = mid; }
        bounds[t] = lo;
    }
    __syncthreads();
    int beg = bounds[0], end = bounds[1];
    int w = t >> 6, j = t & 63;
    float s = 0.0f;
    for (int n = beg + w; n < end; n += 4)
        s += x0[(size_t)n * DIM + j] + x1[(size_t)n * DIM + j];
    hs[w][j] = s;
    __syncthreads();
    if (t < DIM) hs[0][t] = (hs[0][t] + hs[1][t] + hs[2][t] + hs[3][t]) * 0.5f;
    __syncthreads();
    if (t < N_CLASS) {
        int cnt = end - beg;
        float acc = 0.0f;
#pragma unroll
        for (int d = 0; d < DIM; ++d) acc += hs[0][d] * Wout[d * N_CLASS + t];
        out[g * N_CLASS + t] = (cnt > 0) ? (acc / (float)cnt + bout[t]) : 0.0f;
    }
}

extern "C" void kernel_launch(void* const* d_in, const int* in_sizes, int n_in,
                              void* d_out, int out_size, void* d_ws, size_t ws_size,
                              hipStream_t stream) {
    const float* x    = (const float*)d_in[0];
    const float* W0   = (const float*)d_in[1];
    const float* b0   = (const float*)d_in[2];
    const float* W1   = (const float*)d_in[3];
    const float* b1   = (const float*)d_in[4];
    const float* Wout = (const float*)d_in[5];
    const float* bout = (const float*)d_in[6];
    const int* ei_sc  = (const int*)d_in[7];
    const int* ei_fc  = (const int*)d_in[8];
    const int* batch  = (const int*)d_in[9];

    const int* src_sc = ei_sc;
    const int* dst_sc = ei_sc + N_EDGES;
    const int* src_fc = ei_fc;
    const int* dst_fc = ei_fc + N_EDGES;

    // ---- workspace layout (4-byte elements) ----
    char* ws = (char*)d_ws;
    size_t off = 0;
    auto alloc = [&](size_t elems) { void* p = ws + off; off += elems * 4; return p; };
    float* bufA      = (float*)alloc((size_t)N_NODES * DIM);   // sc layer-1 out
    float* bufB      = (float*)alloc((size_t)N_NODES * DIM);   // sc hidden
    float* bufC      = (float*)alloc((size_t)N_NODES * DIM);   // fc hidden
    float* inv_sc    = (float*)alloc(N_NODES);
    float* inv_fc    = (float*)alloc(N_NODES);
    int*   deg_sc    = (int*)alloc(N_NODES);                   // also fill cursor
    int*   deg_fc    = (int*)alloc(N_NODES);
    int*   row_sc    = (int*)alloc(N_NODES + 1);
    int*   row_fc    = (int*)alloc(N_NODES + 1);
    int*   partial   = (int*)alloc(2 * NSCB);
    int*   sorted_sc = (int*)alloc(N_EDGES);
    int*   sorted_fc = (int*)alloc(N_EDGES);
    float* bufD      = (float*)alloc((size_t)N_NODES * DIM);   // fc layer-1 out (optional)
    bool have_bufD = (off <= ws_size);

    const int BLK = 256;
    dim3 blk(BLK);
    int grid_E  = (N_EDGES + BLK - 1) / BLK;
    int grid_N8 = (N_NODES + NPB - 1) / NPB;

    // ---- CSR build ----
    hipMemsetAsync(deg_sc, 0, 2 * (size_t)N_NODES * sizeof(int), stream);
    deg_kernel<<<grid_E, blk, 0, stream>>>(dst_sc, dst_fc, deg_sc, deg_fc);
    scanA_kernel<<<dim3(NSCB, 2), blk, 0, stream>>>(deg_sc, deg_fc, partial);
    scanB_kernel<<<1, 64, 0, stream>>>(partial);
    scanC_kernel<<<dim3(NSCB, 2), blk, 0, stream>>>(deg_sc, deg_fc, partial,
                                                    row_sc, row_fc, inv_sc, inv_fc);
    hipMemsetAsync(deg_sc, 0, 2 * (size_t)N_NODES * sizeof(int), stream);  // cursors
    fill_kernel<<<dim3(grid_E, 2), blk, 0, stream>>>(src_sc, dst_sc, src_fc, dst_fc,
                                                     row_sc, row_fc, deg_sc, deg_fc,
                                                     sorted_sc, sorted_fc);

    // ---- layer 0: both branches in one launch (x -> bufB, bufC) ----
    layer_kernel<<<dim3(grid_N8, 2), LBLK, 0, stream>>>(
        row_sc, sorted_sc, inv_sc, x, W0, b0, bufB,
        row_fc, sorted_fc, inv_fc, x, W1, b1, bufC);

    float* fc_out;
    if (have_bufD) {
        // ---- layer 1: both branches in one launch (bufB->bufA, bufC->bufD) ----
        layer_kernel<<<dim3(grid_N8, 2), LBLK, 0, stream>>>(
            row_sc, sorted_sc, inv_sc, bufB, W0 + DIM * DIM, b0 + DIM, bufA,
            row_fc, sorted_fc, inv_fc, bufC, W1 + DIM * DIM, b1 + DIM, bufD);
        fc_out = bufD;
    } else {
        // fallback: serialize (fc overwrites bufB after sc consumed it)
        layer_kernel<<<dim3(grid_N8, 1), LBLK, 0, stream>>>(
            row_sc, sorted_sc, inv_sc, bufB, W0 + DIM * DIM, b0 + DIM, bufA,
            row_sc, sorted_sc, inv_sc, bufB, W0 + DIM * DIM, b0 + DIM, bufA);
        layer_kernel<<<dim3(grid_N8, 1), LBLK, 0, stream>>>(
            row_fc, sorted_fc, inv_fc, bufC, W1 + DIM * DIM, b1 + DIM, bufB,
            row_fc, sorted_fc, inv_fc, bufC, W1 + DIM * DIM, b1 + DIM, bufB);
        fc_out = bufB;
    }

    // ---- per-graph projection (no atomics, no finalize) ----
    graph_proj_kernel<<<N_GRAPH, 256, 0, stream>>>(bufA, fc_out, Wout, bout, batch,
                                                   (float*)d_out);
}

// Round 6
// 269.007 us; speedup vs baseline: 11.4382x; 1.2937x over previous
//
#include <hip/hip_runtime.h>

#define N_NODES 50000
#define N_EDGES 800000
#define DIM 64
#define N_GRAPH 512
#define N_CLASS 10
#define SCHUNK 512
#define NSCB ((N_NODES + SCHUNK - 1) / SCHUNK)   // 98 blocks per branch
#define NPB 8                                     // nodes per block in layer kernel
#define LBLK (NPB * 64)                           // 512 threads

// ---------------- degree + per-edge rank (both branches) ----------------
// rank[e] = position of edge e within its dst segment (atomic order).
// After this pass deg[] holds the final degree; fill needs NO atomics.
__global__ void degrank_kernel(const int* __restrict__ dst_sc,
                               const int* __restrict__ dst_fc,
                               int* __restrict__ deg_sc,
                               int* __restrict__ deg_fc,
                               int* __restrict__ rank_sc,
                               int* __restrict__ rank_fc) {
    int i = blockIdx.x * blockDim.x + threadIdx.x;
    if (i < N_EDGES) {
        rank_sc[i] = atomicAdd(&deg_sc[dst_sc[i]], 1);
        rank_fc[i] = atomicAdd(&deg_fc[dst_fc[i]], 1);
    }
}

// ---------------- hierarchical scan: A = per-block sums ----------------
__global__ void scanA_kernel(const int* __restrict__ deg_sc,
                             const int* __restrict__ deg_fc,
                             int* __restrict__ partial) {
    const int* deg = blockIdx.y ? deg_fc : deg_sc;
    int base = blockIdx.x * SCHUNK;
    int t = threadIdx.x;
    int s = 0;
    int i0 = base + t, i1 = base + t + 256;
    if (i0 < N_NODES) s += deg[i0];
    if (i1 < N_NODES) s += deg[i1];
    __shared__ int red[256];
    red[t] = s;
    __syncthreads();
    for (int off = 128; off > 0; off >>= 1) {
        if (t < off) red[t] += red[t + off];
        __syncthreads();
    }
    if (t == 0) partial[blockIdx.y * NSCB + blockIdx.x] = red[0];
}

// ---------------- B: exclusive scan of the 2x98 partials ----------------
__global__ void scanB_kernel(int* __restrict__ partial) {
    __shared__ int s[2 * NSCB];
    int t = threadIdx.x;
    for (int k = t; k < 2 * NSCB; k += blockDim.x) s[k] = partial[k];
    __syncthreads();
    if (t < 2) {
        int* p = s + t * NSCB;
        int run = 0;
        for (int i = 0; i < NSCB; ++i) { int v = p[i]; p[i] = run; run += v; }
    }
    __syncthreads();
    for (int k = t; k < 2 * NSCB; k += blockDim.x) partial[k] = s[k];
}

// ---------------- C: per-block local scan -> row offsets + inv ----------------
__global__ void scanC_kernel(const int* __restrict__ deg_sc,
                             const int* __restrict__ deg_fc,
                             const int* __restrict__ partial,
                             int* __restrict__ row_sc, int* __restrict__ row_fc,
                             float* __restrict__ inv_sc, float* __restrict__ inv_fc) {
    const int* deg = blockIdx.y ? deg_fc : deg_sc;
    int* row = blockIdx.y ? row_fc : row_sc;
    float* inv = blockIdx.y ? inv_fc : inv_sc;
    int base = blockIdx.x * SCHUNK;
    int t = threadIdx.x;
    int i0 = base + 2 * t, i1 = i0 + 1;
    int d0 = (i0 < N_NODES) ? deg[i0] : 0;
    int d1 = (i1 < N_NODES) ? deg[i1] : 0;
    __shared__ int s[256];
    s[t] = d0 + d1;
    __syncthreads();
    for (int off = 1; off < 256; off <<= 1) {
        int v = (t >= off) ? s[t - off] : 0;
        __syncthreads();
        s[t] += v;
        __syncthreads();
    }
    int pre = (t == 0) ? 0 : s[t - 1];
    int blockbase = partial[blockIdx.y * NSCB + blockIdx.x];
    int r0 = blockbase + pre;
    if (i0 < N_NODES) { row[i0] = r0;      inv[i0] = 1.0f / fmaxf((float)d0, 1.0f); }
    if (i1 < N_NODES) { row[i1] = r0 + d0; inv[i1] = 1.0f / fmaxf((float)d1, 1.0f); }
    if (blockIdx.x == 0 && t == 0) row[N_NODES] = N_EDGES;  // every edge lands in [0,N)
}

// ---------------- atomic-free counting-sort fill (grid.y = branch) ----------------
__global__ void fill2_kernel(const int* __restrict__ src_sc, const int* __restrict__ dst_sc,
                             const int* __restrict__ rank_sc, const int* __restrict__ row_sc,
                             unsigned short* __restrict__ sorted_sc,
                             const int* __restrict__ src_fc, const int* __restrict__ dst_fc,
                             const int* __restrict__ rank_fc, const int* __restrict__ row_fc,
                             unsigned short* __restrict__ sorted_fc) {
    int e = blockIdx.x * blockDim.x + threadIdx.x;
    if (e >= N_EDGES) return;
    const int *src, *dst, *rank, *row;
    unsigned short* sorted;
    if (blockIdx.y == 0) { src = src_sc; dst = dst_sc; rank = rank_sc; row = row_sc; sorted = sorted_sc; }
    else                 { src = src_fc; dst = dst_fc; rank = rank_fc; row = row_fc; sorted = sorted_fc; }
    int d = dst[e];
    sorted[row[d] + rank[e]] = (unsigned short)src[e];
}

// ---------------- fused gather-aggregate + linear + relu ----------------
// block = 512 threads = 8 waves = 8 nodes.
// Within a wave: 4 edge-groups x 16 lanes; lane covers feature chunk c..c+3 via
// float4 loads. Main loop keeps 4 float4 loads in flight per lane (16 edges/wave-iter).
__global__ void __launch_bounds__(LBLK)
layer_kernel(const int* __restrict__ row_a, const unsigned short* __restrict__ sorted_a,
             const float* __restrict__ inv_a, const float* __restrict__ in_a,
             const float* __restrict__ Wa, const float* __restrict__ ba,
             float* __restrict__ out_a,
             const int* __restrict__ row_b, const unsigned short* __restrict__ sorted_b,
             const float* __restrict__ inv_b, const float* __restrict__ in_b,
             const float* __restrict__ Wb, const float* __restrict__ bb,
             float* __restrict__ out_b) {
    const int* row;  const unsigned short* sorted; const float* inv; const float* in;
    const float* W;  const float* bias; float* out;
    if (blockIdx.y == 0) { row = row_a; sorted = sorted_a; inv = inv_a; in = in_a; W = Wa; bias = ba; out = out_a; }
    else                 { row = row_b; sorted = sorted_b; inv = inv_b; in = in_b; W = Wb; bias = bb; out = out_b; }

    __shared__ float Ws[DIM * DIM];
    __shared__ float As[NPB][DIM];
    int t = threadIdx.x;
    for (int k = t; k < DIM * DIM; k += LBLK) Ws[k] = W[k];

    int w = t >> 6, lane = t & 63;
    int eg = lane >> 4;            // edge slot within group-of-4
    int c  = (lane & 15) << 2;     // feature chunk base
    int n = blockIdx.x * NPB + w;
    if (n < N_NODES) {
        int beg = row[n], end = row[n + 1];
        float iv = inv[n];
        float ax = 0.f, ay = 0.f, az = 0.f, aw = 0.f;
        int k = beg;
        for (; k + 16 <= end; k += 16) {     // 16 edges/wave-iter, 4 float4 in flight
            int s0 = sorted[k + eg];
            int s1 = sorted[k + 4 + eg];
            int s2 = sorted[k + 8 + eg];
            int s3 = sorted[k + 12 + eg];
            const float4 v0 = *(const float4*)(in + (size_t)s0 * DIM + c);
            const float4 v1 = *(const float4*)(in + (size_t)s1 * DIM + c);
            const float4 v2 = *(const float4*)(in + (size_t)s2 * DIM + c);
            const float4 v3 = *(const float4*)(in + (size_t)s3 * DIM + c);
            ax += (v0.x + v1.x) + (v2.x + v3.x);
            ay += (v0.y + v1.y) + (v2.y + v3.y);
            az += (v0.z + v1.z) + (v2.z + v3.z);
            aw += (v0.w + v1.w) + (v2.w + v3.w);
        }
        if (k + 8 <= end) {
            int s0 = sorted[k + eg];
            int s1 = sorted[k + 4 + eg];
            const float4 v0 = *(const float4*)(in + (size_t)s0 * DIM + c);
            const float4 v1 = *(const float4*)(in + (size_t)s1 * DIM + c);
            ax += v0.x + v1.x; ay += v0.y + v1.y;
            az += v0.z + v1.z; aw += v0.w + v1.w;
            k += 8;
        }
        int k0 = k + eg;
        if (k0 < end) {
            const float4 v = *(const float4*)(in + (size_t)sorted[k0] * DIM + c);
            ax += v.x; ay += v.y; az += v.z; aw += v.w;
        }
        int k1 = k + 4 + eg;
        if (k1 < end) {
            const float4 v = *(const float4*)(in + (size_t)sorted[k1] * DIM + c);
            ax += v.x; ay += v.y; az += v.z; aw += v.w;
        }
        // reduce across the 4 edge-groups (lane ^ 16, lane ^ 32)
        ax += __shfl_xor(ax, 16, 64); ay += __shfl_xor(ay, 16, 64);
        az += __shfl_xor(az, 16, 64); aw += __shfl_xor(aw, 16, 64);
        ax += __shfl_xor(ax, 32, 64); ay += __shfl_xor(ay, 32, 64);
        az += __shfl_xor(az, 32, 64); aw += __shfl_xor(aw, 32, 64);
        if (eg == 0) {
            float4 r = make_float4(ax * iv, ay * iv, az * iv, aw * iv);
            *(float4*)&As[w][c] = r;
        }
    }
    __syncthreads();
    if (n < N_NODES) {
        int j = lane;
        float acc = 0.0f;
#pragma unroll
        for (int d = 0; d < DIM; ++d) acc += As[w][d] * Ws[d * DIM + j];
        out[(size_t)n * DIM + j] = fmaxf(acc + bias[j], 0.0f);
    }
}

// ---------------- per-graph projection (batch_idx sorted -> contiguous ranges) ----------------
__global__ void graph_proj_kernel(const float* __restrict__ x0, const float* __restrict__ x1,
                                  const float* __restrict__ Wout, const float* __restrict__ bout,
                                  const int* __restrict__ batch, float* __restrict__ out) {
    int g = blockIdx.x;
    __shared__ int bounds[2];
    __shared__ float hs[4][DIM];
    int t = threadIdx.x;
    if (t < 2) {
        int target = g + t;           // lower_bound(batch, g) and lower_bound(batch, g+1)
        int lo = 0, hi = N_NODES;
        while (lo < hi) { int mid = (lo + hi) >> 1; if (batch[mid] < target) lo = mid + 1; else hi = mid; }
        bounds[t] = lo;
    }
    __syncthreads();
    int beg = bounds[0], end = bounds[1];
    int w = t >> 6, j = t & 63;
    float s = 0.0f;
    for (int n = beg + w; n < end; n += 4)
        s += x0[(size_t)n * DIM + j] + x1[(size_t)n * DIM + j];
    hs[w][j] = s;
    __syncthreads();
    if (t < DIM) hs[0][t] = (hs[0][t] + hs[1][t] + hs[2][t] + hs[3][t]) * 0.5f;
    __syncthreads();
    if (t < N_CLASS) {
        int cnt = end - beg;
        float acc = 0.0f;
#pragma unroll
        for (int d = 0; d < DIM; ++d) acc += hs[0][d] * Wout[d * N_CLASS + t];
        out[g * N_CLASS + t] = (cnt > 0) ? (acc / (float)cnt + bout[t]) : 0.0f;
    }
}

extern "C" void kernel_launch(void* const* d_in, const int* in_sizes, int n_in,
                              void* d_out, int out_size, void* d_ws, size_t ws_size,
                              hipStream_t stream) {
    const float* x    = (const float*)d_in[0];
    const float* W0   = (const float*)d_in[1];
    const float* b0   = (const float*)d_in[2];
    const float* W1   = (const float*)d_in[3];
    const float* b1   = (const float*)d_in[4];
    const float* Wout = (const float*)d_in[5];
    const float* bout = (const float*)d_in[6];
    const int* ei_sc  = (const int*)d_in[7];
    const int* ei_fc  = (const int*)d_in[8];
    const int* batch  = (const int*)d_in[9];

    const int* src_sc = ei_sc;
    const int* dst_sc = ei_sc + N_EDGES;
    const int* src_fc = ei_fc;
    const int* dst_fc = ei_fc + N_EDGES;

    // ---- workspace layout (4-byte units) ----
    char* ws = (char*)d_ws;
    size_t off = 0;
    auto alloc = [&](size_t elems) { void* p = ws + off; off += elems * 4; return p; };
    float* bufA      = (float*)alloc((size_t)N_NODES * DIM);   // sc layer-1 out
    float* bufB      = (float*)alloc((size_t)N_NODES * DIM);   // sc hidden
    float* bufC      = (float*)alloc((size_t)N_NODES * DIM);   // fc hidden
    float* inv_sc    = (float*)alloc(N_NODES);
    float* inv_fc    = (float*)alloc(N_NODES);
    int*   deg_sc    = (int*)alloc(N_NODES);
    int*   deg_fc    = (int*)alloc(N_NODES);
    int*   row_sc    = (int*)alloc(N_NODES + 1);
    int*   row_fc    = (int*)alloc(N_NODES + 1);
    int*   partial   = (int*)alloc(2 * NSCB);
    int*   rank_sc   = (int*)alloc(N_EDGES);
    int*   rank_fc   = (int*)alloc(N_EDGES);
    unsigned short* sorted_sc = (unsigned short*)alloc(N_EDGES / 2);  // ushort, E even
    unsigned short* sorted_fc = (unsigned short*)alloc(N_EDGES / 2);
    float* bufD      = (float*)alloc((size_t)N_NODES * DIM);   // fc layer-1 out (optional)
    bool have_bufD = (off <= ws_size);

    const int BLK = 256;
    dim3 blk(BLK);
    int grid_E  = (N_EDGES + BLK - 1) / BLK;
    int grid_N8 = (N_NODES + NPB - 1) / NPB;

    // ---- CSR build ----
    hipMemsetAsync(deg_sc, 0, 2 * (size_t)N_NODES * sizeof(int), stream);
    degrank_kernel<<<grid_E, blk, 0, stream>>>(dst_sc, dst_fc, deg_sc, deg_fc,
                                               rank_sc, rank_fc);
    scanA_kernel<<<dim3(NSCB, 2), blk, 0, stream>>>(deg_sc, deg_fc, partial);
    scanB_kernel<<<1, 64, 0, stream>>>(partial);
    scanC_kernel<<<dim3(NSCB, 2), blk, 0, stream>>>(deg_sc, deg_fc, partial,
                                                    row_sc, row_fc, inv_sc, inv_fc);
    fill2_kernel<<<dim3(grid_E, 2), blk, 0, stream>>>(
        src_sc, dst_sc, rank_sc, row_sc, sorted_sc,
        src_fc, dst_fc, rank_fc, row_fc, sorted_fc);

    // ---- layer 0: both branches in one launch (x -> bufB, bufC) ----
    layer_kernel<<<dim3(grid_N8, 2), LBLK, 0, stream>>>(
        row_sc, sorted_sc, inv_sc, x, W0, b0, bufB,
        row_fc, sorted_fc, inv_fc, x, W1, b1, bufC);

    float* fc_out;
    if (have_bufD) {
        // ---- layer 1: both branches in one launch (bufB->bufA, bufC->bufD) ----
        layer_kernel<<<dim3(grid_N8, 2), LBLK, 0, stream>>>(
            row_sc, sorted_sc, inv_sc, bufB, W0 + DIM * DIM, b0 + DIM, bufA,
            row_fc, sorted_fc, inv_fc, bufC, W1 + DIM * DIM, b1 + DIM, bufD);
        fc_out = bufD;
    } else {
        // fallback: serialize (fc overwrites bufB after sc consumed it)
        layer_kernel<<<dim3(grid_N8, 1), LBLK, 0, stream>>>(
            row_sc, sorted_sc, inv_sc, bufB, W0 + DIM * DIM, b0 + DIM, bufA,
            row_sc, sorted_sc, inv_sc, bufB, W0 + DIM * DIM, b0 + DIM, bufA);
        layer_kernel<<<dim3(grid_N8, 1), LBLK, 0, stream>>>(
            row_fc, sorted_fc, inv_fc, bufC, W1 + DIM * DIM, b1 + DIM, bufB,
            row_fc, sorted_fc, inv_fc, bufC, W1 + DIM * DIM, b1 + DIM, bufB);
        fc_out = bufB;
    }

    // ---- per-graph projection (no atomics, no finalize) ----
    graph_proj_kernel<<<N_GRAPH, 256, 0, stream>>>(bufA, fc_out, Wout, bout, batch,
                                                   (float*)d_out);
}